// Round 8
// baseline (134.979 us; speedup 1.0000x reference)
//
#include <hip/hip_runtime.h>
#include <cstdint>

// Problem constants: view1 (B=8, C=4, H=256, W=256) fp32, F 3x3 fp32.
constexpr int Hh = 256, Ww = 256, BCc = 32;   // BC = B*C = 32 channels

typedef _Float16 half2v __attribute__((ext_vector_type(2)));
typedef __fp16   fp16x2 __attribute__((ext_vector_type(2)));
typedef uint32_t uint4v __attribute__((ext_vector_type(4)));

static __device__ inline float fdot2acc(half2v a, half2v b, float c) {
#if __has_builtin(__builtin_amdgcn_fdot2)
    return __builtin_amdgcn_fdot2(a, b, c, false);
#else
    return fmaf((float)a.x, (float)b.x, fmaf((float)a.y, (float)b.y, c));
#endif
}
static __device__ inline half2v pack2(float a, float b) {
#if __has_builtin(__builtin_amdgcn_cvt_pkrtz)
    fp16x2 r = __builtin_amdgcn_cvt_pkrtz(a, b);   // one v_cvt_pkrtz_f16_f32
    return __builtin_bit_cast(half2v, r);
#else
    half2v r; r.x = (_Float16)a; r.y = (_Float16)b; return r;
#endif
}

// ---------------------------------------------------------------------------
// Pack view1 (ch,H,W) f32 -> Tpair[r][u][ch] = half2(row r, row r+1), row 256
// zero-padded. One block per r; LDS-staged so global stores are linear.
// ---------------------------------------------------------------------------
__global__ __launch_bounds__(256) void fume_pack(const float* __restrict__ in,
                                                 uint32_t* __restrict__ Tp) {
    __shared__ uint32_t lds[256 * 33];          // [u][ch], stride 33
    const int u = threadIdx.x;
    const int r = blockIdx.x;
    const bool has1 = (r < Hh - 1);
#pragma unroll
    for (int ch = 0; ch < BCc; ++ch) {          // coalesced per channel plane
        float a = in[ch * (Hh * Ww) + r * Ww + u];
        float b = has1 ? in[ch * (Hh * Ww) + (r + 1) * Ww + u] : 0.f;
        half2v p; p.x = (_Float16)a; p.y = (_Float16)b;
        uint32_t w; __builtin_memcpy(&w, &p, 4);
        lds[u * 33 + ch] = w;
    }
    __syncthreads();
    uint32_t* dst = Tp + (size_t)r * (Ww * BCc);
#pragma unroll
    for (int j = 0; j < 32; ++j) {              // linear coalesced stores
        int o = j * 256 + threadIdx.x;          // 0..8191
        int uu = o >> 5, ch = o & 31;
        dst[o] = lds[uu * 33 + ch];
    }
}

// ---------------------------------------------------------------------------
// Main. Wave = 16-px x-strip x 4 channel-parts. KEY (R8): the u-loop is
// WAVE-UNIFORM — bounds are the wave-union of per-pixel clip windows
// (shfl-reduce + readfirstlane -> scalar loop). At the same u the strip's 16
// pixels hit ~1-3 distinct 128B cells (dv/dx<=0.19) -> intra-instruction
// dedup cuts L1 line-touches ~8x vs per-lane-u loops. Per-step masks
// (= the v in (-1,256) condition) zero out-of-window lanes automatically.
// Two u-half waves per strip, combined via LDS (R7 structure).
// ---------------------------------------------------------------------------
template <bool USE_T>
__global__ __launch_bounds__(256, 8) void fume_main(const void* __restrict__ srcv,
                                                    const float* __restrict__ Fm,
                                                    float* __restrict__ out) {
    __shared__ float red[2][16][32];             // 4KB; swizzled below
    const int t    = threadIdx.x;
    const int lane = t & 63;
    const int wv   = t >> 6;                     // 0..3
    const int part = lane & 3;                   // channel part, ch0 = part*8
    const int pxx  = lane >> 2;                  // 0..15 in x-strip
    const int uh   = wv & 1;                     // u-half of this wave
    const int ly   = wv >> 1;                    // y within block (0..1)
    const int x = ((int)blockIdx.x & 15) * 16 + pxx;
    const int y = ((int)blockIdx.x >> 4) * 2 + ly;
    const int pix = y * Ww + x;

    // Epipolar line l1 = F^T x2, normalized (reference op order).
    float xf = (float)x, yf = (float)y;
    float a = Fm[0] * xf + Fm[3] * yf + Fm[6];
    float b = Fm[1] * xf + Fm[4] * yf + Fm[7];
    float c = Fm[2] * xf + Fm[5] * yf + Fm[8];
    float n = sqrtf(a * a + b * b) + 1e-12f;
    a /= n; b /= n; c /= n;

    float alpha, beta;
    int u_lo, u_hi;
    if (fabsf(b) > 1e-6f) {                      // 'ok' mask
        alpha = -a / b;                          // v(u) = alpha*u + beta
        beta  = -c / b;
        u_lo = 0; u_hi = Ww - 1;
        // Clip: contribution exactly 0 unless v in (-1, 256). Per-step masks
        // re-check exactly, so conservative rounding here is harmless.
        if (fabsf(alpha) > 1e-12f) {
            float inv = 1.f / alpha;
            float t0 = (-1.f  - beta) * inv, t1 = (256.f - beta) * inv;
            int lo = (int)floorf(fminf(t0, t1)); // cvt saturates on overflow
            int hi = (int)ceilf (fmaxf(t0, t1));
            u_lo = lo > 0 ? lo : 0;
            u_hi = hi < (Ww - 1) ? hi : (Ww - 1);
        } else if (beta <= -1.f || beta >= 256.f) {
            u_lo = 1 << 20; u_hi = -(1 << 20);   // empty
        }
    } else {                                     // whole pixel is zero
        alpha = 0.f; beta = -1e6f;               // v always far out -> w=0
        u_lo = 1 << 20; u_hi = -(1 << 20);
    }

    // Wave-union of clip windows -> uniform scalar bounds.
    int lo = u_lo, hi = u_hi;
#pragma unroll
    for (int off = 1; off < 64; off <<= 1) {
        int l2 = __shfl_xor(lo, off, 64);
        int h2 = __shfl_xor(hi, off, 64);
        lo = lo < l2 ? lo : l2;
        hi = hi > h2 ? hi : h2;
    }
    lo = __builtin_amdgcn_readfirstlane(lo);
    hi = __builtin_amdgcn_readfirstlane(hi);

    float acc[8];
#pragma unroll
    for (int k = 0; k < 8; ++k) acc[k] = 0.f;

    if (lo <= hi) {
        // This wave's u-half of the union range (both halves keep the 16-px
        // coalescing front; uniform bounds within each wave).
        int mid = lo + ((hi - lo + 1) >> 1);
        int us = uh ? mid : lo;
        int ue = uh ? hi  : mid - 1;
        if (!USE_T) { us = uh ? 1 : lo; ue = uh ? 0 : hi; }  // fallback: h0 all

        const char*  srcT = (const char*)srcv + (part << 5);
        const float* srcF = (const float*)srcv;
        float v = fmaf(alpha, (float)us, beta);  // then v += alpha per step

#pragma unroll 2
        for (int u = us; u <= ue; ++u) {
            float rf = floorf(v);
            float f  = v - rf;
            int   ri = (int)rf;
            int   rb = ri < 0 ? 0 : (ri > Hh - 1 ? Hh - 1 : ri);
            bool inb = ((unsigned)ri < (unsigned)Hh);
            // Weights vs cell rb = rows (rb, rb+1). ri==-1 -> f*row0;
            // ri==255 -> w1 hits the zero-padded row 256. Out of (-1,256):
            // both weights 0 (this is what masks out-of-window lanes).
            float w0 = inb ? (1.f - f) : ((ri == -1) ? f : 0.f);
            float w1 = inb ? f : 0.f;
            if constexpr (USE_T) {
                half2v wp = pack2(w0, w1);
                const uint4v* cell = (const uint4v*)
                    (srcT + ((size_t)(unsigned)u << 7) + ((size_t)rb << 15));
                uint4v c0 = cell[0], c1 = cell[1];
#pragma unroll
                for (int i = 0; i < 4; ++i) {
                    uint32_t w = c0[i]; half2v s; __builtin_memcpy(&s, &w, 4);
                    acc[i] = fdot2acc(wp, s, acc[i]);
                }
#pragma unroll
                for (int i = 0; i < 4; ++i) {
                    uint32_t w = c1[i]; half2v s; __builtin_memcpy(&s, &w, 4);
                    acc[4 + i] = fdot2acc(wp, s, acc[4 + i]);
                }
            } else {
                int ch0 = part * 8;
#pragma unroll
                for (int k = 0; k < 8; ++k) {
                    float s0 = srcF[(size_t)(ch0 + k) * (Hh * Ww) + rb * Ww + u];
                    float s1 = (rb < Hh - 1)
                                 ? srcF[(size_t)(ch0 + k) * (Hh * Ww) + (rb + 1) * Ww + u]
                                 : 0.f;
                    acc[k] = fmaf(w0, s0, fmaf(w1, s1, acc[k]));
                }
            }
            v += alpha;
        }
    }

    // Combine the two u-half waves of this strip via LDS (swizzled: 2-way max).
    if (uh == 1) {
#pragma unroll
        for (int k = 0; k < 8; ++k)
            red[ly][pxx][(part * 8 + k + pxx) & 31] = acc[k];
    }
    __syncthreads();
    if (uh == 0) {
#pragma unroll
        for (int k = 0; k < 8; ++k) {
            int ch = part * 8 + k;
            float s = acc[k] + red[ly][pxx][(ch + pxx) & 31];
            out[(size_t)ch * (Hh * Ww) + pix] = s;
        }
    }
}

extern "C" void kernel_launch(void* const* d_in, const int* in_sizes, int n_in,
                              void* d_out, int out_size, void* d_ws, size_t ws_size,
                              hipStream_t stream) {
    const float* view1 = (const float*)d_in[0];   // 8*4*256*256 fp32
    const float* Fm    = (const float*)d_in[1];   // 9 fp32, row-major 3x3
    float* out = (float*)d_out;

    constexpr size_t t_bytes = (size_t)Hh * Ww * BCc * 4;   // 8 MiB fp16 pairs
    constexpr int n_blocks = 16 * (Hh / 2);                 // 2048
    if (ws_size >= t_bytes) {
        uint32_t* Tp = (uint32_t*)d_ws;
        fume_pack<<<Hh, 256, 0, stream>>>(view1, Tp);
        fume_main<true><<<n_blocks, 256, 0, stream>>>(Tp, Fm, out);
    } else {
        fume_main<false><<<n_blocks, 256, 0, stream>>>(view1, Fm, out);
    }
}